// Round 2
// baseline (142.750 us; speedup 1.0000x reference)
//
#include <hip/hip_runtime.h>

// Problem constants (fixed by the reference): B=512 rows, T=32768, K=64, R=4.
#define T_LEN  32768
#define B_ROWS 512
#define KSEL   64.0f
#define CHUNK  16
#define HALO   10   // dependency cone of the 4 damping passes: 1+2+3+4

// sigmoid via v_exp_f32 + v_rcp_f32 (~1 ulp each; verified absmax 1.5e-05 vs np ref)
__device__ __forceinline__ float fast_sigmoid(float x) {
    return __builtin_amdgcn_rcpf(1.0f + __expf(-x));
}

// a * min(2/(1+a+b), 1):  2/(1+s) >= 1  <=>  s <= 1
__device__ __forceinline__ float damp(float a, float b) {
    float s = a + b;
    float f = (s > 1.0f) ? 2.0f * __builtin_amdgcn_rcpf(1.0f + s) : 1.0f;
    return a * f;
}

__device__ __forceinline__ float clamped_temp(const float* log_temp) {
    float t = expf(log_temp[0]);
    return fminf(fmaxf(t, 0.1f), 10.0f);
}

// ---- Kernel A: per-row budget = sum(sigmoid(scores/temp)) -> row_sums[row] ----
__global__ __launch_bounds__(256)
void rowsum_kernel(const float* __restrict__ scores,
                   const float* __restrict__ log_temp,
                   float* __restrict__ row_sums) {
    const int row = blockIdx.x;
    const int tid = threadIdx.x;
    const float inv_temp = 1.0f / clamped_temp(log_temp);

    const float4* srow4 = (const float4*)(scores + (size_t)row * T_LEN);
    float sum = 0.0f;
    for (int i = tid; i < T_LEN / 4; i += 256) {   // 32 iters/thread
        float4 v = srow4[i];
        sum += fast_sigmoid(v.x * inv_temp);
        sum += fast_sigmoid(v.y * inv_temp);
        sum += fast_sigmoid(v.z * inv_temp);
        sum += fast_sigmoid(v.w * inv_temp);
    }
    #pragma unroll
    for (int off = 32; off > 0; off >>= 1)
        sum += __shfl_down(sum, off, 64);
    __shared__ float red[4];
    const int wid = tid >> 6, lane = tid & 63;
    if (lane == 0) red[wid] = sum;
    __syncthreads();
    if (tid == 0) row_sums[row] = red[0] + red[1] + red[2] + red[3];
}

// ---- Kernel B: y = sigmoid*scale, 4 damping passes in registers, store ----
__global__ __launch_bounds__(256)
void select_kernel(const float* __restrict__ scores,
                   const float* __restrict__ log_temp,
                   const float* __restrict__ row_sums,
                   float* __restrict__ out) {
    const int gid  = blockIdx.x * 256 + threadIdx.x;   // 2048 threads per row
    const int row  = gid >> 11;
    const int col0 = (gid & 2047) << 4;                // 16 outputs/thread
    const float* srow = scores + (size_t)row * T_LEN;

    const float inv_temp = 1.0f / clamped_temp(log_temp);
    const float budget   = fmaxf(row_sums[row], 1e-6f);
    const float scale    = fminf(KSEL / budget, 1.0f);

    float w[CHUNK + HALO];
    if (col0 + CHUNK + HALO <= T_LEN) {
        const float4* p = (const float4*)(srow + col0);   // col0 % 16 == 0 -> aligned
        float4 a0 = p[0], a1 = p[1], a2 = p[2], a3 = p[3], a4 = p[4], a5 = p[5];
        w[0]=a0.x;  w[1]=a0.y;  w[2]=a0.z;  w[3]=a0.w;
        w[4]=a1.x;  w[5]=a1.y;  w[6]=a1.z;  w[7]=a1.w;
        w[8]=a2.x;  w[9]=a2.y;  w[10]=a2.z; w[11]=a2.w;
        w[12]=a3.x; w[13]=a3.y; w[14]=a3.z; w[15]=a3.w;
        w[16]=a4.x; w[17]=a4.y; w[18]=a4.z; w[19]=a4.w;
        w[20]=a5.x; w[21]=a5.y; w[22]=a5.z; w[23]=a5.w;
        w[24] = srow[col0 + 24];
        w[25] = srow[col0 + 25];
    } else {
        // only the final window of each row wraps (jnp.roll semantics)
        #pragma unroll
        for (int j = 0; j < CHUNK + HALO; ++j)
            w[j] = srow[(col0 + j) & (T_LEN - 1)];
    }

    #pragma unroll
    for (int j = 0; j < CHUNK + HALO; ++j)
        w[j] = fast_sigmoid(w[j] * inv_temp) * scale;

    // 4 passes, in-place ascending: w[j+d] read pre-update, matching vectorized ref
    #pragma unroll
    for (int j = 0; j < 25; ++j) w[j] = damp(w[j], w[j + 1]);
    #pragma unroll
    for (int j = 0; j < 23; ++j) w[j] = damp(w[j], w[j + 2]);
    #pragma unroll
    for (int j = 0; j < 20; ++j) w[j] = damp(w[j], w[j + 3]);
    #pragma unroll
    for (int j = 0; j < 16; ++j) w[j] = damp(w[j], w[j + 4]);

    if (col0 == 0) w[0] = 0.0f;   // y[:,0] = 0, applied after damping (ref order)

    float4* q = (float4*)(out + (size_t)row * T_LEN + col0);
    q[0] = make_float4(w[0],  w[1],  w[2],  w[3]);
    q[1] = make_float4(w[4],  w[5],  w[6],  w[7]);
    q[2] = make_float4(w[8],  w[9],  w[10], w[11]);
    q[3] = make_float4(w[12], w[13], w[14], w[15]);
}

extern "C" void kernel_launch(void* const* d_in, const int* in_sizes, int n_in,
                              void* d_out, int out_size, void* d_ws, size_t ws_size,
                              hipStream_t stream) {
    const float* scores = (const float*)d_in[0];
    const float* lt     = (const float*)d_in[1];
    float*       out    = (float*)d_out;
    float*       sums   = (float*)d_ws;   // 512 floats; written by A before B reads

    rowsum_kernel<<<B_ROWS, 256, 0, stream>>>(scores, lt, sums);
    select_kernel<<<(B_ROWS * (T_LEN / CHUNK)) / 256, 256, 0, stream>>>(scores, lt, sums, out);
}